// Round 4
// baseline (908.675 us; speedup 1.0000x reference)
//
#include <hip/hip_runtime.h>
#include <hip/hip_bf16.h>
#include <math.h>

// DistributedAFNO2D: out = x + irfft2( blockMLP( rfft2(x, ortho) ), ortho )
// B=2, C=768, H=W=256, 8 blocks x 96 ch, KW = 129 frequency cols.
// F in d_ws: bf16-packed complex (u32 = [imag:bf16 | real:bf16]), layout (B*C, KW, H).
// Passes: rowfft -> [fused: colFFT + MFMA mix + inv colFFT] -> rowifft.
// Column spectrum lives in bit-reversed slot order (mix is pointwise -> free).

#define LAMBDA_SS 0.01f

typedef unsigned int u32;
typedef __attribute__((ext_vector_type(8))) short bf16x8;
typedef __attribute__((ext_vector_type(4))) float f32x4;

__device__ __forceinline__ u32 pack_bf16(float r, float i) {
  union { float f; u32 u; } ur, ui;
  ur.f = r; ui.f = i;
  u32 rb = (ur.u + 0x7FFFu + ((ur.u >> 16) & 1u)) >> 16;
  u32 ib = (ui.u + 0x7FFFu + ((ui.u >> 16) & 1u)) >> 16;
  return (ib << 16) | (rb & 0xFFFFu);
}

__device__ __forceinline__ float2 unpack_bf16(u32 p) {
  union { u32 u; float f; } a, b;
  a.u = (p & 0xFFFFu) << 16;
  b.u = (p & 0xFFFF0000u);
  return make_float2(a.f, b.f);
}

__device__ __forceinline__ float sshrink(float v) {
  return (v > LAMBDA_SS) ? v - LAMBDA_SS : ((v < -LAMBDA_SS) ? v + LAMBDA_SS : 0.f);
}

// ---------------- register FFT machinery ----------------
__device__ __forceinline__ float2 cadd(float2 a, float2 b){ return make_float2(a.x+b.x, a.y+b.y); }
__device__ __forceinline__ float2 csub(float2 a, float2 b){ return make_float2(a.x-b.x, a.y-b.y); }
__device__ __forceinline__ float2 cmul(float2 a, float2 b){
  return make_float2(fmaf(a.x,b.x,-a.y*b.y), fmaf(a.x,b.y,a.y*b.x));
}
__device__ __forceinline__ float2 cmulj(float2 a, float si){
  return make_float2(-si*a.y, si*a.x);
}
__device__ __forceinline__ float2 shflx(float2 v, int m){
  return make_float2(__shfl_xor(v.x, m, 64), __shfl_xor(v.y, m, 64));
}
__device__ __forceinline__ float2 shfll(float2 v, int l){
  return make_float2(__shfl(v.x, l, 64), __shfl(v.y, l, 64));
}
__device__ __forceinline__ int brev6(int x){ return (int)(__brev((u32)x) >> 26); }

struct Tw { float2 t128, t64, t32, t16, t8, t4; float si; };

__device__ __forceinline__ float2 mkTw(int e, float si){
  float a = (float)e * 0.0245436926f;   // 2*pi/256
  return make_float2(cosf(a), si*sinf(a));
}
__device__ __forceinline__ Tw make_tw(int lane, float si){
  Tw w; w.si = si;
  w.t128 = mkTw(lane, si);
  w.t64  = mkTw(2*lane, si);
  w.t32  = mkTw((lane&31)*4, si);
  w.t16  = mkTw((lane&15)*8, si);
  w.t8   = mkTw((lane&7)*16, si);
  w.t4   = mkTw((lane&3)*32, si);
  return w;
}

__device__ __forceinline__ float2 bfly_dif(float2 v, int h, float2 th, int lane){
  float2 p = shflx(v, h);
  float sx = (lane & h) ? -1.f : 1.f;
  float2 s = make_float2(fmaf(sx, v.x, p.x), fmaf(sx, v.y, p.y));
  if (lane & h) s = cmul(s, th);
  return s;
}
__device__ __forceinline__ float2 bfly_dit(float2 v, int h, float2 th, int lane){
  if (lane & h) v = cmul(v, th);
  float2 p = shflx(v, h);
  float sx = (lane & h) ? -1.f : 1.f;
  return make_float2(fmaf(sx, v.x, p.x), fmaf(sx, v.y, p.y));
}

// Forward DIF: natural input at d = lane + 64r; output X[brev8(d)] at slot d.
__device__ __forceinline__ void fft256_dif(float2 v[4], int lane, const Tw& T){
  float2 t128b = cmulj(T.t128, T.si);
  { float2 a=v[0], b=v[2]; v[0]=cadd(a,b); v[2]=cmul(csub(a,b), T.t128);
    float2 c=v[1], d=v[3]; v[1]=cadd(c,d); v[3]=cmul(csub(c,d), t128b); }
  { float2 a=v[0], b=v[1]; v[0]=cadd(a,b); v[1]=cmul(csub(a,b), T.t64);
    float2 c=v[2], d=v[3]; v[2]=cadd(c,d); v[3]=cmul(csub(c,d), T.t64); }
#pragma unroll
  for (int r=0;r<4;++r) v[r]=bfly_dif(v[r],32,T.t32,lane);
#pragma unroll
  for (int r=0;r<4;++r) v[r]=bfly_dif(v[r],16,T.t16,lane);
#pragma unroll
  for (int r=0;r<4;++r) v[r]=bfly_dif(v[r],8,T.t8,lane);
#pragma unroll
  for (int r=0;r<4;++r) v[r]=bfly_dif(v[r],4,T.t4,lane);
#pragma unroll
  for (int r=0;r<4;++r){
    float2 p=shflx(v[r],2);
    float sx=(lane&2)?-1.f:1.f;
    float2 s=make_float2(fmaf(sx,v[r].x,p.x), fmaf(sx,v[r].y,p.y));
    if ((lane&3)==3) s=cmulj(s,T.si);
    v[r]=s;
  }
#pragma unroll
  for (int r=0;r<4;++r){
    float2 p=shflx(v[r],1);
    float sx=(lane&1)?-1.f:1.f;
    v[r]=make_float2(fmaf(sx,v[r].x,p.x), fmaf(sx,v[r].y,p.y));
  }
}

// Inverse DIT: input X[brev8(d)] at slot d; natural output at slot d.
__device__ __forceinline__ void fft256_dit(float2 v[4], int lane, const Tw& T){
#pragma unroll
  for (int r=0;r<4;++r){
    float2 p=shflx(v[r],1);
    float sx=(lane&1)?-1.f:1.f;
    v[r]=make_float2(fmaf(sx,v[r].x,p.x), fmaf(sx,v[r].y,p.y));
  }
#pragma unroll
  for (int r=0;r<4;++r){
    float2 w=v[r];
    if ((lane&3)==3) w=cmulj(w,T.si);
    float2 p=shflx(w,2);
    float sx=(lane&2)?-1.f:1.f;
    v[r]=make_float2(fmaf(sx,w.x,p.x), fmaf(sx,w.y,p.y));
  }
#pragma unroll
  for (int r=0;r<4;++r) v[r]=bfly_dit(v[r],4,T.t4,lane);
#pragma unroll
  for (int r=0;r<4;++r) v[r]=bfly_dit(v[r],8,T.t8,lane);
#pragma unroll
  for (int r=0;r<4;++r) v[r]=bfly_dit(v[r],16,T.t16,lane);
#pragma unroll
  for (int r=0;r<4;++r) v[r]=bfly_dit(v[r],32,T.t32,lane);
  { v[1]=cmul(v[1],T.t64); float2 a=v[0]; v[0]=cadd(a,v[1]); v[1]=csub(a,v[1]);
    v[3]=cmul(v[3],T.t64); float2 c=v[2]; v[2]=cadd(c,v[3]); v[3]=csub(c,v[3]); }
  { v[2]=cmul(v[2],T.t128); v[3]=cmul(v[3], cmulj(T.t128,T.si));
    float2 a=v[0]; v[0]=cadd(a,v[2]); v[2]=csub(a,v[2]);
    float2 b=v[1]; v[1]=cadd(b,v[3]); v[3]=csub(b,v[3]); }
}

__device__ __forceinline__ int stage_row(int kw){ return 33*(kw&3) + (kw>>2); }

// ---------------- Pass 1: row rfft, 2 real rows per complex FFT ----------------
__global__ __launch_bounds__(256) void k_rowfft(const float* __restrict__ x, u32* __restrict__ F) {
  __shared__ u32 stage[131*65];
  const int bc = blockIdx.x >> 2, hc = blockIdx.x & 3;
  const int tid = threadIdx.x, wave = tid >> 6, lane = tid & 63;
  Tw T = make_tw(lane, -1.f);
  const int L = brev6(lane);
  const int laneP0 = brev6((64 - L) & 63);
  const int lanePX = 63 - lane;

  for (int rr = 0; rr < 8; ++rr) {
    const int hl0 = wave*16 + rr*2, hl1 = hl0 + 1;
    const float* xa = x + ((size_t)bc*256 + hc*64 + hl0) * 256;
    float2 v[4];
#pragma unroll
    for (int r=0;r<4;++r){ int d = lane + 64*r; v[r] = make_float2(xa[d], xa[256+d]); }
    fft256_dif(v, lane, T);
#define UNSCR(R, RP, C, LP) { \
      float2 z = v[R]; float2 p = shfll(v[RP], LP); \
      float2 A  = make_float2(0.5f*(z.x+p.x), 0.5f*(z.y-p.y)); \
      float2 Bv = make_float2(0.5f*(z.y+p.y), 0.5f*(p.x-z.x)); \
      int kw = 4*L + (C); \
      if (kw <= 128) { int row = stage_row(kw); \
        stage[row*65 + hl0] = pack_bf16(A.x, A.y); \
        stage[row*65 + hl1] = pack_bf16(Bv.x, Bv.y); } }
    UNSCR(0, 0, 0, laneP0)
    UNSCR(1, 1, 2, lanePX)
    UNSCR(2, 3, 1, lanePX)
    UNSCR(3, 2, 3, lanePX)
#undef UNSCR
  }
  __syncthreads();
  for (int idx = tid; idx < 129*64; idx += 256) {
    int kw = idx >> 6, hl = idx & 63;
    F[((size_t)bc*129 + kw)*256 + hc*64 + hl] = stage[stage_row(kw)*65 + hl];
  }
}

// ---------------- Weight prep ----------------
__global__ __launch_bounds__(256) void k_prep_w(const float2* __restrict__ w1,
                                                const float2* __restrict__ w2,
                                                u32* __restrict__ Wt) {
  const int blk = blockIdx.x;      // k*2 + layer
  const int k = blk >> 1, layer = blk & 1;
  const float2* w = (layer == 0 ? w1 : w2) + (size_t)k * 96 * 96;
  u32* out = Wt + (size_t)blk * 18432;
  for (int idx = threadIdx.x; idx < 9216; idx += 256) {
    int o = idx % 96, i = idx / 96;
    float2 v = w[i * 96 + o];
    out[(2 * o) * 96 + i]     = pack_bf16(v.x, -v.y);
    out[(2 * o + 1) * 96 + i] = pack_bf16(v.y, v.x);
  }
}

// ---------------- Fused pass: colFFT + MFMA mix + inv colFFT, per (b,k,kw) -------
// 512 thr / 8 waves (2 wm x 4 wn). LDS reused in-place:
//   phase A/B: Dlds[n=0..255][kk=0..191] bf16, byte = n*384 + kk*2, swz ^((n&7)<<4)
//   phase C:   Clds[c=0..95][n] u32, dword = c*258 + n
#define CM_LDS_BYTES 99072

__global__ __launch_bounds__(512, 2) void k_colmix(u32* __restrict__ F,
    const u32* __restrict__ Wt,
    const float2* __restrict__ b1, const float2* __restrict__ b2) {
  extern __shared__ char smem[];

  const int bi = (blockIdx.x & 7) * 258 + (blockIdx.x >> 3);  // XCD swizzle (2064 = 8*258)
  const int kw = bi % 129;
  const int bk = bi / 129;
  const int k = bk & 7, b = bk >> 3;
  const int t = threadIdx.x;
  const int lane = t & 63, wave = t >> 6;
  const int wm = wave >> 2, wn = wave & 3;
  const int lrow = lane & 15;
  const int g = lane >> 4;
  const int lk = g * 16;

  const size_t chstride = 129 * 256;
  const size_t colbase = (((size_t)(b*768 + k*96)) * 129 + kw) * 256;

  // ---- phase A: load 12 columns/wave, fwd FFT, store to Dlds (scaled 1/256) ----
  {
    Tw Tf = make_tw(lane, -1.f);
    u32 raw[12][4];
#pragma unroll
    for (int cc = 0; cc < 12; ++cc) {
      const u32* p = F + colbase + (size_t)(wave*12 + cc) * chstride;
#pragma unroll
      for (int r = 0; r < 4; ++r) raw[cc][r] = p[lane + 64*r];
    }
    const float s = 1.f/256.f;
#pragma unroll
    for (int cc = 0; cc < 12; ++cc) {
      float2 v[4];
#pragma unroll
      for (int r = 0; r < 4; ++r) v[r] = unpack_bf16(raw[cc][r]);
      fft256_dif(v, lane, Tf);
      const int c = wave*12 + cc;
#pragma unroll
      for (int r = 0; r < 4; ++r) {
        int n = lane + 64*r;
        int byte = n*384 + c*4;
        *reinterpret_cast<u32*>(smem + (byte ^ ((n&7)<<4))) = pack_bf16(v[r].x*s, v[r].y*s);
      }
    }
  }
  __syncthreads();

  const bf16x8* W1v = reinterpret_cast<const bf16x8*>(Wt + (size_t)(k*2 + 0) * 18432);
  const bf16x8* W2v = reinterpret_cast<const bf16x8*>(Wt + (size_t)(k*2 + 1) * 18432);

  f32x4 acc[6][4];

  // ---- layer 1: acc = W1 x D ----
#pragma unroll
  for (int mi = 0; mi < 6; ++mi)
#pragma unroll
    for (int ni = 0; ni < 4; ++ni) acc[mi][ni] = (f32x4)0.f;
  {
    bf16x8 af[2][6];
#pragma unroll
    for (int mi = 0; mi < 6; ++mi)
      af[0][mi] = W1v[(wm*96 + mi*16 + lrow)*24 + g];
#pragma unroll
    for (int ks = 0; ks < 6; ++ks) {
      if (ks < 5) {
#pragma unroll
        for (int mi = 0; mi < 6; ++mi)
          af[(ks+1)&1][mi] = W1v[(wm*96 + mi*16 + lrow)*24 + (ks+1)*4 + g];
      }
      bf16x8 bf[4];
#pragma unroll
      for (int ni = 0; ni < 4; ++ni) {
        int n = wn*64 + ni*16 + lrow;
        int byte = n*384 + ks*64 + lk;
        bf[ni] = *reinterpret_cast<bf16x8*>(smem + (byte ^ ((n&7)<<4)));
      }
#pragma unroll
      for (int ni = 0; ni < 4; ++ni)
#pragma unroll
        for (int mi = 0; mi < 6; ++mi)
          acc[mi][ni] = __builtin_amdgcn_mfma_f32_16x16x32_bf16(af[ks&1][mi], bf[ni], acc[mi][ni], 0, 0, 0);
    }
  }
  __syncthreads();   // all Dlds reads done

  // ---- O1 = relu(acc + b1) -> Dlds in place ----
  {
    const float2* b1k = b1 + k * 96;
#pragma unroll
    for (int mi = 0; mi < 6; ++mi) {
      int m0 = wm*96 + mi*16 + 4*g;
      int o0 = m0 >> 1;
      float2 ba = b1k[o0], bb = b1k[o0 + 1];
#pragma unroll
      for (int ni = 0; ni < 4; ++ni) {
        int n = wn*64 + ni*16 + lrow;
        f32x4 v = acc[mi][ni];
        u32 lo = pack_bf16(fmaxf(v[0] + ba.x, 0.f), fmaxf(v[1] + ba.y, 0.f));
        u32 hi = pack_bf16(fmaxf(v[2] + bb.x, 0.f), fmaxf(v[3] + bb.y, 0.f));
        int byte = n*384 + m0*2;
        *reinterpret_cast<uint2*>(smem + (byte ^ ((n&7)<<4))) = make_uint2(lo, hi);
      }
    }
  }
  __syncthreads();

  // ---- layer 2: acc = W2 x O1 ----
#pragma unroll
  for (int mi = 0; mi < 6; ++mi)
#pragma unroll
    for (int ni = 0; ni < 4; ++ni) acc[mi][ni] = (f32x4)0.f;
  {
    bf16x8 af[2][6];
#pragma unroll
    for (int mi = 0; mi < 6; ++mi)
      af[0][mi] = W2v[(wm*96 + mi*16 + lrow)*24 + g];
#pragma unroll
    for (int ks = 0; ks < 6; ++ks) {
      if (ks < 5) {
#pragma unroll
        for (int mi = 0; mi < 6; ++mi)
          af[(ks+1)&1][mi] = W2v[(wm*96 + mi*16 + lrow)*24 + (ks+1)*4 + g];
      }
      bf16x8 bf[4];
#pragma unroll
      for (int ni = 0; ni < 4; ++ni) {
        int n = wn*64 + ni*16 + lrow;
        int byte = n*384 + ks*64 + lk;
        bf[ni] = *reinterpret_cast<bf16x8*>(smem + (byte ^ ((n&7)<<4)));
      }
#pragma unroll
      for (int ni = 0; ni < 4; ++ni)
#pragma unroll
        for (int mi = 0; mi < 6; ++mi)
          acc[mi][ni] = __builtin_amdgcn_mfma_f32_16x16x32_bf16(af[ks&1][mi], bf[ni], acc[mi][ni], 0, 0, 0);
    }
  }
  __syncthreads();   // all O1 reads done

  // ---- epilogue: bias2 + softshrink -> Clds [c][n] (dword = c*258 + n) ----
  {
    u32* Clds = reinterpret_cast<u32*>(smem);
    const float2* b2k = b2 + k * 96;
#pragma unroll
    for (int mi = 0; mi < 6; ++mi) {
      int m0 = wm*96 + mi*16 + 4*g;
      int o0 = m0 >> 1;
      float2 ca = b2k[o0], cb = b2k[o0 + 1];
#pragma unroll
      for (int ni = 0; ni < 4; ++ni) {
        int n = wn*64 + ni*16 + lrow;
        f32x4 v = acc[mi][ni];
        Clds[o0*258 + n]       = pack_bf16(sshrink(v[0] + ca.x), sshrink(v[1] + ca.y));
        Clds[(o0 + 1)*258 + n] = pack_bf16(sshrink(v[2] + cb.x), sshrink(v[3] + cb.y));
      }
    }
  }
  __syncthreads();

  // ---- phase C: inverse FFT per column, write F back (scaled 1/256) ----
  {
    const u32* Clds = reinterpret_cast<const u32*>(smem);
    Tw Ti = make_tw(lane, 1.f);
    const float s = 1.f/256.f;
#pragma unroll
    for (int cc = 0; cc < 12; ++cc) {
      const int c = wave*12 + cc;
      float2 v[4];
#pragma unroll
      for (int r = 0; r < 4; ++r) v[r] = unpack_bf16(Clds[c*258 + lane + 64*r]);
      fft256_dit(v, lane, Ti);
      u32* p = F + colbase + (size_t)c * chstride;
#pragma unroll
      for (int r = 0; r < 4; ++r) p[lane + 64*r] = pack_bf16(v[r].x*s, v[r].y*s);
    }
  }
}

// ---------------- Pass 5: row irfft (Hermitian ext), 2 rows per FFT, + bias ------
__global__ __launch_bounds__(256) void k_rowifft(const u32* __restrict__ F,
                                                 const float* __restrict__ x,
                                                 float* __restrict__ out) {
  __shared__ u32 stage[131*65];
  const int bc = blockIdx.x >> 2, hc = blockIdx.x & 3;
  const int tid = threadIdx.x, wave = tid >> 6, lane = tid & 63;
  Tw T = make_tw(lane, 1.f);
  for (int idx = tid; idx < 129*64; idx += 256) {
    int kw = idx >> 6, hl = idx & 63;
    stage[stage_row(kw)*65 + hl] = F[((size_t)bc*129 + kw)*256 + hc*64 + hl];
  }
  __syncthreads();

  const int L = brev6(lane);
  for (int rr = 0; rr < 8; ++rr) {
    const int hl0 = wave*16 + rr*2, hl1 = hl0 + 1;
    float2 v[4];
#pragma unroll
    for (int r=0;r<4;++r) {
      int c = ((r&1)<<1) | (r>>1);
      int kw = 4*L + c;
      int src = (kw <= 128) ? kw : 256 - kw;
      float sg = (kw <= 128) ? 1.f : -1.f;
      int row = stage_row(src);
      float2 a = unpack_bf16(stage[row*65 + hl0]);
      float2 b = unpack_bf16(stage[row*65 + hl1]);
      a.y *= sg; b.y *= sg;
      if (kw == 0 || kw == 128) { a.y = 0.f; b.y = 0.f; }
      v[r] = make_float2(a.x - b.y, a.y + b.x);
    }
    fft256_dit(v, lane, T);
    const float* xa = x   + ((size_t)bc*256 + hc*64 + hl0) * 256;
    float*       oa = out + ((size_t)bc*256 + hc*64 + hl0) * 256;
#pragma unroll
    for (int r=0;r<4;++r) {
      int d = lane + 64*r;
      oa[d]       = v[r].x + xa[d];
      oa[256 + d] = v[r].y + xa[256 + d];
    }
  }
}

extern "C" void kernel_launch(void* const* d_in, const int* in_sizes, int n_in,
                              void* d_out, int out_size, void* d_ws, size_t ws_size,
                              hipStream_t stream) {
  const float* x   = (const float*)d_in[0];
  const float2* w1 = (const float2*)d_in[1];
  const float2* b1 = (const float2*)d_in[2];
  const float2* w2 = (const float2*)d_in[3];
  const float2* b2 = (const float2*)d_in[4];
  float* out = (float*)d_out;
  u32* F = (u32*)d_ws;            // 1536*129*256*4 B ~ 203 MB
  u32* Wt = (u32*)d_out;          // d_out head as scratch; overwritten by k_rowifft

  (void)hipFuncSetAttribute(reinterpret_cast<const void*>(k_colmix),
                            hipFuncAttributeMaxDynamicSharedMemorySize, CM_LDS_BYTES);

  const int n_rows_blocks = 1536 * 4;
  const int n_cm_blocks   = 2 * 8 * 129;   // 2064 = 8 * 258

  k_prep_w<<<16, 256, 0, stream>>>(w1, w2, Wt);
  k_rowfft<<<n_rows_blocks, 256, 0, stream>>>(x, F);
  k_colmix<<<n_cm_blocks, 512, CM_LDS_BYTES, stream>>>(F, Wt, b1, b2);
  k_rowifft<<<n_rows_blocks, 256, 0, stream>>>(F, x, out);
}

// Round 5
// 886.776 us; speedup vs baseline: 1.0247x; 1.0247x over previous
//
#include <hip/hip_runtime.h>
#include <hip/hip_bf16.h>
#include <math.h>

// DistributedAFNO2D: out = x + irfft2( blockMLP( rfft2(x, ortho) ), ortho )
// B=2, C=768, H=W=256, 8 blocks x 96 ch, KW = 129 frequency cols.
// F in d_ws: bf16-packed complex (u32 = [imag:bf16 | real:bf16]), layout (B*C, KW, H).
// Passes: rowfft -> [fused: colFFT + MFMA mix + inv colFFT] -> rowifft.
// colmix uses register FFT with layout d = 4*lane + r (vectorized uint4 F I/O);
// column spectrum exists only inside the fused kernel (brev slot order, free).

#define LAMBDA_SS 0.01f

typedef unsigned int u32;
typedef __attribute__((ext_vector_type(8))) short bf16x8;
typedef __attribute__((ext_vector_type(4))) float f32x4;

__device__ __forceinline__ u32 pack_bf16(float r, float i) {
  union { float f; u32 u; } ur, ui;
  ur.f = r; ui.f = i;
  u32 rb = (ur.u + 0x7FFFu + ((ur.u >> 16) & 1u)) >> 16;
  u32 ib = (ui.u + 0x7FFFu + ((ui.u >> 16) & 1u)) >> 16;
  return (ib << 16) | (rb & 0xFFFFu);
}

__device__ __forceinline__ float2 unpack_bf16(u32 p) {
  union { u32 u; float f; } a, b;
  a.u = (p & 0xFFFFu) << 16;
  b.u = (p & 0xFFFF0000u);
  return make_float2(a.f, b.f);
}

__device__ __forceinline__ float sshrink(float v) {
  return (v > LAMBDA_SS) ? v - LAMBDA_SS : ((v < -LAMBDA_SS) ? v + LAMBDA_SS : 0.f);
}

// ---------------- register FFT machinery (shared helpers) ----------------
__device__ __forceinline__ float2 cadd(float2 a, float2 b){ return make_float2(a.x+b.x, a.y+b.y); }
__device__ __forceinline__ float2 csub(float2 a, float2 b){ return make_float2(a.x-b.x, a.y-b.y); }
__device__ __forceinline__ float2 cmul(float2 a, float2 b){
  return make_float2(fmaf(a.x,b.x,-a.y*b.y), fmaf(a.x,b.y,a.y*b.x));
}
__device__ __forceinline__ float2 cmulj(float2 a, float si){  // a * (si*i)
  return make_float2(-si*a.y, si*a.x);
}
__device__ __forceinline__ float2 shflx(float2 v, int m){
  return make_float2(__shfl_xor(v.x, m, 64), __shfl_xor(v.y, m, 64));
}
__device__ __forceinline__ float2 shfll(float2 v, int l){
  return make_float2(__shfl(v.x, l, 64), __shfl(v.y, l, 64));
}
__device__ __forceinline__ int brev6(int x){ return (int)(__brev((u32)x) >> 26); }

// ======== layout A: d = lane + 64r (row kernels, unchanged from round 3) ========
struct Tw { float2 t128, t64, t32, t16, t8, t4; float si; };

__device__ __forceinline__ float2 mkTw(int e, float si){
  float a = (float)e * 0.0245436926f;   // 2*pi/256
  return make_float2(cosf(a), si*sinf(a));
}
__device__ __forceinline__ Tw make_tw(int lane, float si){
  Tw w; w.si = si;
  w.t128 = mkTw(lane, si);
  w.t64  = mkTw(2*lane, si);
  w.t32  = mkTw((lane&31)*4, si);
  w.t16  = mkTw((lane&15)*8, si);
  w.t8   = mkTw((lane&7)*16, si);
  w.t4   = mkTw((lane&3)*32, si);
  return w;
}

__device__ __forceinline__ float2 bfly_dif(float2 v, int h, float2 th, int lane){
  float2 p = shflx(v, h);
  float sx = (lane & h) ? -1.f : 1.f;
  float2 s = make_float2(fmaf(sx, v.x, p.x), fmaf(sx, v.y, p.y));
  if (lane & h) s = cmul(s, th);
  return s;
}
__device__ __forceinline__ float2 bfly_dit(float2 v, int h, float2 th, int lane){
  if (lane & h) v = cmul(v, th);
  float2 p = shflx(v, h);
  float sx = (lane & h) ? -1.f : 1.f;
  return make_float2(fmaf(sx, v.x, p.x), fmaf(sx, v.y, p.y));
}

__device__ __forceinline__ void fft256_dif(float2 v[4], int lane, const Tw& T){
  float2 t128b = cmulj(T.t128, T.si);
  { float2 a=v[0], b=v[2]; v[0]=cadd(a,b); v[2]=cmul(csub(a,b), T.t128);
    float2 c=v[1], d=v[3]; v[1]=cadd(c,d); v[3]=cmul(csub(c,d), t128b); }
  { float2 a=v[0], b=v[1]; v[0]=cadd(a,b); v[1]=cmul(csub(a,b), T.t64);
    float2 c=v[2], d=v[3]; v[2]=cadd(c,d); v[3]=cmul(csub(c,d), T.t64); }
#pragma unroll
  for (int r=0;r<4;++r) v[r]=bfly_dif(v[r],32,T.t32,lane);
#pragma unroll
  for (int r=0;r<4;++r) v[r]=bfly_dif(v[r],16,T.t16,lane);
#pragma unroll
  for (int r=0;r<4;++r) v[r]=bfly_dif(v[r],8,T.t8,lane);
#pragma unroll
  for (int r=0;r<4;++r) v[r]=bfly_dif(v[r],4,T.t4,lane);
#pragma unroll
  for (int r=0;r<4;++r){
    float2 p=shflx(v[r],2);
    float sx=(lane&2)?-1.f:1.f;
    float2 s=make_float2(fmaf(sx,v[r].x,p.x), fmaf(sx,v[r].y,p.y));
    if ((lane&3)==3) s=cmulj(s,T.si);
    v[r]=s;
  }
#pragma unroll
  for (int r=0;r<4;++r){
    float2 p=shflx(v[r],1);
    float sx=(lane&1)?-1.f:1.f;
    v[r]=make_float2(fmaf(sx,v[r].x,p.x), fmaf(sx,v[r].y,p.y));
  }
}

__device__ __forceinline__ void fft256_dit(float2 v[4], int lane, const Tw& T){
#pragma unroll
  for (int r=0;r<4;++r){
    float2 p=shflx(v[r],1);
    float sx=(lane&1)?-1.f:1.f;
    v[r]=make_float2(fmaf(sx,v[r].x,p.x), fmaf(sx,v[r].y,p.y));
  }
#pragma unroll
  for (int r=0;r<4;++r){
    float2 w=v[r];
    if ((lane&3)==3) w=cmulj(w,T.si);
    float2 p=shflx(w,2);
    float sx=(lane&2)?-1.f:1.f;
    v[r]=make_float2(fmaf(sx,w.x,p.x), fmaf(sx,w.y,p.y));
  }
#pragma unroll
  for (int r=0;r<4;++r) v[r]=bfly_dit(v[r],4,T.t4,lane);
#pragma unroll
  for (int r=0;r<4;++r) v[r]=bfly_dit(v[r],8,T.t8,lane);
#pragma unroll
  for (int r=0;r<4;++r) v[r]=bfly_dit(v[r],16,T.t16,lane);
#pragma unroll
  for (int r=0;r<4;++r) v[r]=bfly_dit(v[r],32,T.t32,lane);
  { v[1]=cmul(v[1],T.t64); float2 a=v[0]; v[0]=cadd(a,v[1]); v[1]=csub(a,v[1]);
    v[3]=cmul(v[3],T.t64); float2 c=v[2]; v[2]=cadd(c,v[3]); v[3]=csub(c,v[3]); }
  { v[2]=cmul(v[2],T.t128); v[3]=cmul(v[3], cmulj(T.t128,T.si));
    float2 a=v[0]; v[0]=cadd(a,v[2]); v[2]=csub(a,v[2]);
    float2 b=v[1]; v[1]=cadd(b,v[3]); v[3]=csub(b,v[3]); }
}

// ======== layout B: d = 4*lane + r (colmix; vectorized uint4 I/O) ========
// Twiddles tws[s][r] = W_si^{((4*lane+r)<<s)&127}, via squaring chain.
__device__ __forceinline__ void make_tws4(int lane, float si, float2 tws[6][4]) {
#pragma unroll
  for (int r=0;r<4;++r){
    int e = (4*lane + r) & 127;
    float a = si * (float)e * 0.0245436926f;
    float sn, cs;
    sincosf(a, &sn, &cs);
    float2 t = make_float2(cs, sn);
    tws[0][r] = t;
#pragma unroll
    for (int s=1; s<6; ++s) {
      float2 sq = cmul(t, t);
      if (e & 64) { sq.x = -sq.x; sq.y = -sq.y; }
      e = (2*e) & 127;
      t = sq;
      tws[s][r] = t;
    }
  }
}

// Forward DIF: natural input at d=4l+r; output X[brev8(d)] at slot d.
__device__ __forceinline__ void fft256_dif4(float2 v[4], int lane,
                                            const float2 tws[6][4], float si){
#pragma unroll
  for (int s=0;s<6;++s){
    const int m = 32>>s;
#pragma unroll
    for (int r=0;r<4;++r){
      float2 p = shflx(v[r], m);
      float sx = (lane & m) ? -1.f : 1.f;
      float2 t = make_float2(fmaf(sx, v[r].x, p.x), fmaf(sx, v[r].y, p.y));
      float2 tm = cmul(t, tws[s][r]);
      v[r] = (lane & m) ? tm : t;
    }
  }
  { float2 a0=v[0], a2=v[2]; v[0]=cadd(a0,a2); v[2]=csub(a0,a2);
    float2 a1=v[1], a3=v[3]; v[1]=cadd(a1,a3); v[3]=cmulj(csub(a1,a3), si); }
  { float2 a=v[0]; v[0]=cadd(a,v[1]); v[1]=csub(a,v[1]);
    float2 c=v[2]; v[2]=cadd(c,v[3]); v[3]=csub(c,v[3]); }
}

// Inverse DIT: input X[brev8(d)] at slot d; natural output at d=4l+r.
__device__ __forceinline__ void fft256_dit4(float2 v[4], int lane,
                                            const float2 tws[6][4], float si){
  { float2 a=v[0]; v[0]=cadd(a,v[1]); v[1]=csub(a,v[1]);
    float2 c=v[2]; v[2]=cadd(c,v[3]); v[3]=csub(c,v[3]); }
  { v[3] = cmulj(v[3], si);
    float2 a0=v[0]; v[0]=cadd(a0,v[2]); v[2]=csub(a0,v[2]);
    float2 a1=v[1]; v[1]=cadd(a1,v[3]); v[3]=csub(a1,v[3]); }
#pragma unroll
  for (int s=5;s>=0;--s){
    const int m = 32>>s;
#pragma unroll
    for (int r=0;r<4;++r){
      float2 wm_ = cmul(v[r], tws[s][r]);
      float2 w = (lane & m) ? wm_ : v[r];
      float2 p = shflx(w, m);
      float sx = (lane & m) ? -1.f : 1.f;
      v[r] = make_float2(fmaf(sx, w.x, p.x), fmaf(sx, w.y, p.y));
    }
  }
}

__device__ __forceinline__ int stage_row(int kw){ return 33*(kw&3) + (kw>>2); }
// Dlds swizzle: slot(n) spreads rows 4l+r writes AND 16-row GEMM reads
__device__ __forceinline__ int dslot(int n){ return (((n>>2)&7) ^ ((n&3)<<1)) << 4; }

// ---------------- Pass 1: row rfft, 2 real rows per complex FFT ----------------
__global__ __launch_bounds__(256) void k_rowfft(const float* __restrict__ x, u32* __restrict__ F) {
  __shared__ u32 stage[131*65];
  const int bc = blockIdx.x >> 2, hc = blockIdx.x & 3;
  const int tid = threadIdx.x, wave = tid >> 6, lane = tid & 63;
  Tw T = make_tw(lane, -1.f);
  const int L = brev6(lane);
  const int laneP0 = brev6((64 - L) & 63);
  const int lanePX = 63 - lane;

  for (int rr = 0; rr < 8; ++rr) {
    const int hl0 = wave*16 + rr*2, hl1 = hl0 + 1;
    const float* xa = x + ((size_t)bc*256 + hc*64 + hl0) * 256;
    float2 v[4];
#pragma unroll
    for (int r=0;r<4;++r){ int d = lane + 64*r; v[r] = make_float2(xa[d], xa[256+d]); }
    fft256_dif(v, lane, T);
#define UNSCR(R, RP, C, LP) { \
      float2 z = v[R]; float2 p = shfll(v[RP], LP); \
      float2 A  = make_float2(0.5f*(z.x+p.x), 0.5f*(z.y-p.y)); \
      float2 Bv = make_float2(0.5f*(z.y+p.y), 0.5f*(p.x-z.x)); \
      int kw = 4*L + (C); \
      if (kw <= 128) { int row = stage_row(kw); \
        stage[row*65 + hl0] = pack_bf16(A.x, A.y); \
        stage[row*65 + hl1] = pack_bf16(Bv.x, Bv.y); } }
    UNSCR(0, 0, 0, laneP0)
    UNSCR(1, 1, 2, lanePX)
    UNSCR(2, 3, 1, lanePX)
    UNSCR(3, 2, 3, lanePX)
#undef UNSCR
  }
  __syncthreads();
  for (int idx = tid; idx < 129*64; idx += 256) {
    int kw = idx >> 6, hl = idx & 63;
    F[((size_t)bc*129 + kw)*256 + hc*64 + hl] = stage[stage_row(kw)*65 + hl];
  }
}

// ---------------- Weight prep ----------------
__global__ __launch_bounds__(256) void k_prep_w(const float2* __restrict__ w1,
                                                const float2* __restrict__ w2,
                                                u32* __restrict__ Wt) {
  const int blk = blockIdx.x;      // k*2 + layer
  const int k = blk >> 1, layer = blk & 1;
  const float2* w = (layer == 0 ? w1 : w2) + (size_t)k * 96 * 96;
  u32* out = Wt + (size_t)blk * 18432;
  for (int idx = threadIdx.x; idx < 9216; idx += 256) {
    int o = idx % 96, i = idx / 96;
    float2 v = w[i * 96 + o];
    out[(2 * o) * 96 + i]     = pack_bf16(v.x, -v.y);
    out[(2 * o + 1) * 96 + i] = pack_bf16(v.y, v.x);
  }
}

// ---------------- Fused pass: colFFT + MFMA mix + inv colFFT, per (b,k,kw) -------
// 1024 thr / 16 waves (4 wm x 4 wn). LDS (99072 B) reused in-place:
//   phases A/B: Dlds[n=0..255][kk=0..191] bf16, byte = n*384 + kk*2, XOR dslot(n)
//   phase C:    Clds[c=0..95][n] u32, dword = c*258 + n
#define CM_LDS_BYTES 99072

__global__ __launch_bounds__(1024, 4) void k_colmix(u32* __restrict__ F,
    const u32* __restrict__ Wt,
    const float2* __restrict__ b1, const float2* __restrict__ b2) {
  extern __shared__ char smem[];

  const int bi = (blockIdx.x & 7) * 258 + (blockIdx.x >> 3);  // XCD swizzle (2064 = 8*258)
  const int kw = bi % 129;
  const int bk = bi / 129;
  const int k = bk & 7, b = bk >> 3;
  const int t = threadIdx.x;
  const int lane = t & 63, wave = t >> 6;
  const int wm = wave >> 2, wn = wave & 3;   // M = 4x48, N = 4x64
  const int lrow = lane & 15;
  const int g = lane >> 4;

  const size_t chstride = 129 * 256;
  const size_t colbase = (((size_t)(b*768 + k*96)) * 129 + kw) * 256;

  // ---- phase A: 6 columns/wave, uint4 loads, fwd FFT, scatter to Dlds ----
  {
    uint4 raw[6];
#pragma unroll
    for (int cc = 0; cc < 6; ++cc)
      raw[cc] = *reinterpret_cast<const uint4*>(F + colbase + (size_t)(wave*6 + cc)*chstride + 4*lane);

    float2 tws[6][4];
    make_tws4(lane, -1.f, tws);
    const float s = 1.f/256.f;
#pragma unroll
    for (int pp = 0; pp < 3; ++pp) {
      float2 va[4], vb[4];
      va[0]=unpack_bf16(raw[2*pp].x);   va[1]=unpack_bf16(raw[2*pp].y);
      va[2]=unpack_bf16(raw[2*pp].z);   va[3]=unpack_bf16(raw[2*pp].w);
      vb[0]=unpack_bf16(raw[2*pp+1].x); vb[1]=unpack_bf16(raw[2*pp+1].y);
      vb[2]=unpack_bf16(raw[2*pp+1].z); vb[3]=unpack_bf16(raw[2*pp+1].w);
      fft256_dif4(va, lane, tws, -1.f);
      fft256_dif4(vb, lane, tws, -1.f);
      const int c0 = wave*6 + 2*pp;
#pragma unroll
      for (int r = 0; r < 4; ++r) {
        int n = 4*lane + r;
        int byte = (n*384 + c0*4) ^ dslot(n);
        *reinterpret_cast<uint2*>(smem + byte) =
            make_uint2(pack_bf16(va[r].x*s, va[r].y*s), pack_bf16(vb[r].x*s, vb[r].y*s));
      }
    }
  }
  __syncthreads();

  const bf16x8* W1v = reinterpret_cast<const bf16x8*>(Wt + (size_t)(k*2 + 0) * 18432);
  const bf16x8* W2v = reinterpret_cast<const bf16x8*>(Wt + (size_t)(k*2 + 1) * 18432);

  f32x4 acc[3][4];

  // ---- layer 1: acc = W1 x D ----
#pragma unroll
  for (int mi = 0; mi < 3; ++mi)
#pragma unroll
    for (int ni = 0; ni < 4; ++ni) acc[mi][ni] = (f32x4)0.f;
  {
    bf16x8 af[2][3];
#pragma unroll
    for (int mi = 0; mi < 3; ++mi)
      af[0][mi] = W1v[(wm*48 + mi*16 + lrow)*24 + g];
#pragma unroll
    for (int ks = 0; ks < 6; ++ks) {
      if (ks < 5) {
#pragma unroll
        for (int mi = 0; mi < 3; ++mi)
          af[(ks+1)&1][mi] = W1v[(wm*48 + mi*16 + lrow)*24 + (ks+1)*4 + g];
      }
      bf16x8 bf[4];
#pragma unroll
      for (int ni = 0; ni < 4; ++ni) {
        int n = wn*64 + ni*16 + lrow;
        int byte = (n*384 + ks*64 + g*16) ^ dslot(n);
        bf[ni] = *reinterpret_cast<bf16x8*>(smem + byte);
      }
#pragma unroll
      for (int ni = 0; ni < 4; ++ni)
#pragma unroll
        for (int mi = 0; mi < 3; ++mi)
          acc[mi][ni] = __builtin_amdgcn_mfma_f32_16x16x32_bf16(af[ks&1][mi], bf[ni], acc[mi][ni], 0, 0, 0);
    }
  }
  __syncthreads();

  // ---- O1 = relu(acc + b1) -> Dlds in place ----
  {
    const float2* b1k = b1 + k * 96;
#pragma unroll
    for (int mi = 0; mi < 3; ++mi) {
      int m0 = wm*48 + mi*16 + 4*g;
      int o0 = m0 >> 1;
      float2 ba = b1k[o0], bb = b1k[o0 + 1];
#pragma unroll
      for (int ni = 0; ni < 4; ++ni) {
        int n = wn*64 + ni*16 + lrow;
        f32x4 v = acc[mi][ni];
        u32 lo = pack_bf16(fmaxf(v[0] + ba.x, 0.f), fmaxf(v[1] + ba.y, 0.f));
        u32 hi = pack_bf16(fmaxf(v[2] + bb.x, 0.f), fmaxf(v[3] + bb.y, 0.f));
        int byte = (n*384 + m0*2) ^ dslot(n);
        *reinterpret_cast<uint2*>(smem + byte) = make_uint2(lo, hi);
      }
    }
  }
  __syncthreads();

  // ---- layer 2: acc = W2 x O1 ----
#pragma unroll
  for (int mi = 0; mi < 3; ++mi)
#pragma unroll
    for (int ni = 0; ni < 4; ++ni) acc[mi][ni] = (f32x4)0.f;
  {
    bf16x8 af[2][3];
#pragma unroll
    for (int mi = 0; mi < 3; ++mi)
      af[0][mi] = W2v[(wm*48 + mi*16 + lrow)*24 + g];
#pragma unroll
    for (int ks = 0; ks < 6; ++ks) {
      if (ks < 5) {
#pragma unroll
        for (int mi = 0; mi < 3; ++mi)
          af[(ks+1)&1][mi] = W2v[(wm*48 + mi*16 + lrow)*24 + (ks+1)*4 + g];
      }
      bf16x8 bf[4];
#pragma unroll
      for (int ni = 0; ni < 4; ++ni) {
        int n = wn*64 + ni*16 + lrow;
        int byte = (n*384 + ks*64 + g*16) ^ dslot(n);
        bf[ni] = *reinterpret_cast<bf16x8*>(smem + byte);
      }
#pragma unroll
      for (int ni = 0; ni < 4; ++ni)
#pragma unroll
        for (int mi = 0; mi < 3; ++mi)
          acc[mi][ni] = __builtin_amdgcn_mfma_f32_16x16x32_bf16(af[ks&1][mi], bf[ni], acc[mi][ni], 0, 0, 0);
    }
  }
  __syncthreads();

  // ---- epilogue: bias2 + softshrink -> Clds [c][n] (dword = c*258 + n) ----
  {
    u32* Clds = reinterpret_cast<u32*>(smem);
    const float2* b2k = b2 + k * 96;
#pragma unroll
    for (int mi = 0; mi < 3; ++mi) {
      int m0 = wm*48 + mi*16 + 4*g;
      int o0 = m0 >> 1;
      float2 ca = b2k[o0], cb = b2k[o0 + 1];
#pragma unroll
      for (int ni = 0; ni < 4; ++ni) {
        int n = wn*64 + ni*16 + lrow;
        f32x4 v = acc[mi][ni];
        Clds[o0*258 + n]       = pack_bf16(sshrink(v[0] + ca.x), sshrink(v[1] + ca.y));
        Clds[(o0 + 1)*258 + n] = pack_bf16(sshrink(v[2] + cb.x), sshrink(v[3] + cb.y));
      }
    }
  }
  __syncthreads();

  // ---- phase C: inverse FFT per column, uint4 stores back to F ----
  {
    const u32* Clds = reinterpret_cast<const u32*>(smem);
    float2 tws[6][4];
    make_tws4(lane, 1.f, tws);
    const float s = 1.f/256.f;
#pragma unroll
    for (int pp = 0; pp < 3; ++pp) {
      const int c0 = wave*6 + 2*pp;
      float2 va[4], vb[4];
      {
        uint2 q0 = *reinterpret_cast<const uint2*>(Clds + c0*258 + 4*lane);
        uint2 q1 = *reinterpret_cast<const uint2*>(Clds + c0*258 + 4*lane + 2);
        va[0]=unpack_bf16(q0.x); va[1]=unpack_bf16(q0.y);
        va[2]=unpack_bf16(q1.x); va[3]=unpack_bf16(q1.y);
        uint2 q2 = *reinterpret_cast<const uint2*>(Clds + (c0+1)*258 + 4*lane);
        uint2 q3 = *reinterpret_cast<const uint2*>(Clds + (c0+1)*258 + 4*lane + 2);
        vb[0]=unpack_bf16(q2.x); vb[1]=unpack_bf16(q2.y);
        vb[2]=unpack_bf16(q3.x); vb[3]=unpack_bf16(q3.y);
      }
      fft256_dit4(va, lane, tws, 1.f);
      fft256_dit4(vb, lane, tws, 1.f);
      uint4 oa, ob;
      oa.x = pack_bf16(va[0].x*s, va[0].y*s); oa.y = pack_bf16(va[1].x*s, va[1].y*s);
      oa.z = pack_bf16(va[2].x*s, va[2].y*s); oa.w = pack_bf16(va[3].x*s, va[3].y*s);
      ob.x = pack_bf16(vb[0].x*s, vb[0].y*s); ob.y = pack_bf16(vb[1].x*s, vb[1].y*s);
      ob.z = pack_bf16(vb[2].x*s, vb[2].y*s); ob.w = pack_bf16(vb[3].x*s, vb[3].y*s);
      *reinterpret_cast<uint4*>(F + colbase + (size_t)c0*chstride + 4*lane) = oa;
      *reinterpret_cast<uint4*>(F + colbase + (size_t)(c0+1)*chstride + 4*lane) = ob;
    }
  }
}

// ---------------- Pass 5: row irfft (Hermitian ext), 2 rows per FFT, + bias ------
__global__ __launch_bounds__(256) void k_rowifft(const u32* __restrict__ F,
                                                 const float* __restrict__ x,
                                                 float* __restrict__ out) {
  __shared__ u32 stage[131*65];
  const int bc = blockIdx.x >> 2, hc = blockIdx.x & 3;
  const int tid = threadIdx.x, wave = tid >> 6, lane = tid & 63;
  Tw T = make_tw(lane, 1.f);
  for (int idx = tid; idx < 129*64; idx += 256) {
    int kw = idx >> 6, hl = idx & 63;
    stage[stage_row(kw)*65 + hl] = F[((size_t)bc*129 + kw)*256 + hc*64 + hl];
  }
  __syncthreads();

  const int L = brev6(lane);
  for (int rr = 0; rr < 8; ++rr) {
    const int hl0 = wave*16 + rr*2, hl1 = hl0 + 1;
    float2 v[4];
#pragma unroll
    for (int r=0;r<4;++r) {
      int c = ((r&1)<<1) | (r>>1);
      int kw = 4*L + c;
      int src = (kw <= 128) ? kw : 256 - kw;
      float sg = (kw <= 128) ? 1.f : -1.f;
      int row = stage_row(src);
      float2 a = unpack_bf16(stage[row*65 + hl0]);
      float2 b = unpack_bf16(stage[row*65 + hl1]);
      a.y *= sg; b.y *= sg;
      if (kw == 0 || kw == 128) { a.y = 0.f; b.y = 0.f; }
      v[r] = make_float2(a.x - b.y, a.y + b.x);
    }
    fft256_dit(v, lane, T);
    const float* xa = x   + ((size_t)bc*256 + hc*64 + hl0) * 256;
    float*       oa = out + ((size_t)bc*256 + hc*64 + hl0) * 256;
#pragma unroll
    for (int r=0;r<4;++r) {
      int d = lane + 64*r;
      oa[d]       = v[r].x + xa[d];
      oa[256 + d] = v[r].y + xa[256 + d];
    }
  }
}

extern "C" void kernel_launch(void* const* d_in, const int* in_sizes, int n_in,
                              void* d_out, int out_size, void* d_ws, size_t ws_size,
                              hipStream_t stream) {
  const float* x   = (const float*)d_in[0];
  const float2* w1 = (const float2*)d_in[1];
  const float2* b1 = (const float2*)d_in[2];
  const float2* w2 = (const float2*)d_in[3];
  const float2* b2 = (const float2*)d_in[4];
  float* out = (float*)d_out;
  u32* F = (u32*)d_ws;            // 1536*129*256*4 B ~ 203 MB
  u32* Wt = (u32*)d_out;          // d_out head as scratch; overwritten by k_rowifft

  (void)hipFuncSetAttribute(reinterpret_cast<const void*>(k_colmix),
                            hipFuncAttributeMaxDynamicSharedMemorySize, CM_LDS_BYTES);

  const int n_rows_blocks = 1536 * 4;
  const int n_cm_blocks   = 2 * 8 * 129;   // 2064 = 8 * 258

  k_prep_w<<<16, 256, 0, stream>>>(w1, w2, Wt);
  k_rowfft<<<n_rows_blocks, 256, 0, stream>>>(x, F);
  k_colmix<<<n_cm_blocks, 1024, CM_LDS_BYTES, stream>>>(F, Wt, b1, b2);
  k_rowifft<<<n_rows_blocks, 256, 0, stream>>>(F, x, out);
}

// Round 6
// 880.382 us; speedup vs baseline: 1.0321x; 1.0073x over previous
//
#include <hip/hip_runtime.h>
#include <hip/hip_bf16.h>
#include <math.h>

// DistributedAFNO2D: out = x + irfft2( blockMLP( rfft2(x, ortho) ), ortho )
// B=2, C=768, H=W=256, 8 blocks x 96 ch, KW = 129 frequency cols.
// F in d_ws: bf16-packed complex (u32 = [imag:bf16 | real:bf16]), layout (B*C, KW, H).
// Passes: rowfft -> [fused: colFFT + MFMA mix + inv colFFT] -> rowifft.
// colmix uses register FFT with layout d = 4*lane + r (vectorized uint4 F I/O);
// column spectrum exists only inside the fused kernel (brev slot order, free).

#define LAMBDA_SS 0.01f

typedef unsigned int u32;
typedef __attribute__((ext_vector_type(8))) short bf16x8;
typedef __attribute__((ext_vector_type(4))) float f32x4;

__device__ __forceinline__ u32 pack_bf16(float r, float i) {
  union { float f; u32 u; } ur, ui;
  ur.f = r; ui.f = i;
  u32 rb = (ur.u + 0x7FFFu + ((ur.u >> 16) & 1u)) >> 16;
  u32 ib = (ui.u + 0x7FFFu + ((ui.u >> 16) & 1u)) >> 16;
  return (ib << 16) | (rb & 0xFFFFu);
}

__device__ __forceinline__ float2 unpack_bf16(u32 p) {
  union { u32 u; float f; } a, b;
  a.u = (p & 0xFFFFu) << 16;
  b.u = (p & 0xFFFF0000u);
  return make_float2(a.f, b.f);
}

__device__ __forceinline__ float sshrink(float v) {
  return (v > LAMBDA_SS) ? v - LAMBDA_SS : ((v < -LAMBDA_SS) ? v + LAMBDA_SS : 0.f);
}

// ---------------- register FFT machinery (shared helpers) ----------------
__device__ __forceinline__ float2 cadd(float2 a, float2 b){ return make_float2(a.x+b.x, a.y+b.y); }
__device__ __forceinline__ float2 csub(float2 a, float2 b){ return make_float2(a.x-b.x, a.y-b.y); }
__device__ __forceinline__ float2 cmul(float2 a, float2 b){
  return make_float2(fmaf(a.x,b.x,-a.y*b.y), fmaf(a.x,b.y,a.y*b.x));
}
__device__ __forceinline__ float2 cmulj(float2 a, float si){  // a * (si*i)
  return make_float2(-si*a.y, si*a.x);
}
__device__ __forceinline__ float2 shflx(float2 v, int m){
  return make_float2(__shfl_xor(v.x, m, 64), __shfl_xor(v.y, m, 64));
}
__device__ __forceinline__ float2 shfll(float2 v, int l){
  return make_float2(__shfl(v.x, l, 64), __shfl(v.y, l, 64));
}
__device__ __forceinline__ int brev6(int x){ return (int)(__brev((u32)x) >> 26); }

// ======== layout A: d = lane + 64r (row kernels) ========
struct Tw { float2 t128, t64, t32, t16, t8, t4; float si; };

__device__ __forceinline__ float2 mkTw(int e, float si){
  float a = (float)e * 0.0245436926f;   // 2*pi/256
  return make_float2(cosf(a), si*sinf(a));
}
__device__ __forceinline__ Tw make_tw(int lane, float si){
  Tw w; w.si = si;
  w.t128 = mkTw(lane, si);
  w.t64  = mkTw(2*lane, si);
  w.t32  = mkTw((lane&31)*4, si);
  w.t16  = mkTw((lane&15)*8, si);
  w.t8   = mkTw((lane&7)*16, si);
  w.t4   = mkTw((lane&3)*32, si);
  return w;
}

__device__ __forceinline__ float2 bfly_dif(float2 v, int h, float2 th, int lane){
  float2 p = shflx(v, h);
  float sx = (lane & h) ? -1.f : 1.f;
  float2 s = make_float2(fmaf(sx, v.x, p.x), fmaf(sx, v.y, p.y));
  if (lane & h) s = cmul(s, th);
  return s;
}
__device__ __forceinline__ float2 bfly_dit(float2 v, int h, float2 th, int lane){
  if (lane & h) v = cmul(v, th);
  float2 p = shflx(v, h);
  float sx = (lane & h) ? -1.f : 1.f;
  return make_float2(fmaf(sx, v.x, p.x), fmaf(sx, v.y, p.y));
}

__device__ __forceinline__ void fft256_dif(float2 v[4], int lane, const Tw& T){
  float2 t128b = cmulj(T.t128, T.si);
  { float2 a=v[0], b=v[2]; v[0]=cadd(a,b); v[2]=cmul(csub(a,b), T.t128);
    float2 c=v[1], d=v[3]; v[1]=cadd(c,d); v[3]=cmul(csub(c,d), t128b); }
  { float2 a=v[0], b=v[1]; v[0]=cadd(a,b); v[1]=cmul(csub(a,b), T.t64);
    float2 c=v[2], d=v[3]; v[2]=cadd(c,d); v[3]=cmul(csub(c,d), T.t64); }
#pragma unroll
  for (int r=0;r<4;++r) v[r]=bfly_dif(v[r],32,T.t32,lane);
#pragma unroll
  for (int r=0;r<4;++r) v[r]=bfly_dif(v[r],16,T.t16,lane);
#pragma unroll
  for (int r=0;r<4;++r) v[r]=bfly_dif(v[r],8,T.t8,lane);
#pragma unroll
  for (int r=0;r<4;++r) v[r]=bfly_dif(v[r],4,T.t4,lane);
#pragma unroll
  for (int r=0;r<4;++r){
    float2 p=shflx(v[r],2);
    float sx=(lane&2)?-1.f:1.f;
    float2 s=make_float2(fmaf(sx,v[r].x,p.x), fmaf(sx,v[r].y,p.y));
    if ((lane&3)==3) s=cmulj(s,T.si);
    v[r]=s;
  }
#pragma unroll
  for (int r=0;r<4;++r){
    float2 p=shflx(v[r],1);
    float sx=(lane&1)?-1.f:1.f;
    v[r]=make_float2(fmaf(sx,v[r].x,p.x), fmaf(sx,v[r].y,p.y));
  }
}

__device__ __forceinline__ void fft256_dit(float2 v[4], int lane, const Tw& T){
#pragma unroll
  for (int r=0;r<4;++r){
    float2 p=shflx(v[r],1);
    float sx=(lane&1)?-1.f:1.f;
    v[r]=make_float2(fmaf(sx,v[r].x,p.x), fmaf(sx,v[r].y,p.y));
  }
#pragma unroll
  for (int r=0;r<4;++r){
    float2 w=v[r];
    if ((lane&3)==3) w=cmulj(w,T.si);
    float2 p=shflx(w,2);
    float sx=(lane&2)?-1.f:1.f;
    v[r]=make_float2(fmaf(sx,w.x,p.x), fmaf(sx,w.y,p.y));
  }
#pragma unroll
  for (int r=0;r<4;++r) v[r]=bfly_dit(v[r],4,T.t4,lane);
#pragma unroll
  for (int r=0;r<4;++r) v[r]=bfly_dit(v[r],8,T.t8,lane);
#pragma unroll
  for (int r=0;r<4;++r) v[r]=bfly_dit(v[r],16,T.t16,lane);
#pragma unroll
  for (int r=0;r<4;++r) v[r]=bfly_dit(v[r],32,T.t32,lane);
  { v[1]=cmul(v[1],T.t64); float2 a=v[0]; v[0]=cadd(a,v[1]); v[1]=csub(a,v[1]);
    v[3]=cmul(v[3],T.t64); float2 c=v[2]; v[2]=cadd(c,v[3]); v[3]=csub(c,v[3]); }
  { v[2]=cmul(v[2],T.t128); v[3]=cmul(v[3], cmulj(T.t128,T.si));
    float2 a=v[0]; v[0]=cadd(a,v[2]); v[2]=csub(a,v[2]);
    float2 b=v[1]; v[1]=cadd(b,v[3]); v[3]=csub(b,v[3]); }
}

// ======== layout B: d = 4*lane + r (colmix; vectorized uint4 I/O) ========
__device__ __forceinline__ void make_tws4(int lane, float si, float2 tws[6][4]) {
#pragma unroll
  for (int r=0;r<4;++r){
    int e = (4*lane + r) & 127;
    float a = si * (float)e * 0.0245436926f;
    float sn, cs;
    sincosf(a, &sn, &cs);
    float2 t = make_float2(cs, sn);
    tws[0][r] = t;
#pragma unroll
    for (int s=1; s<6; ++s) {
      float2 sq = cmul(t, t);
      if (e & 64) { sq.x = -sq.x; sq.y = -sq.y; }
      e = (2*e) & 127;
      t = sq;
      tws[s][r] = t;
    }
  }
}

// Forward DIF: natural input at d=4l+r; output X[brev8(d)] at slot d.
__device__ __forceinline__ void fft256_dif4(float2 v[4], int lane,
                                            const float2 tws[6][4], float si){
#pragma unroll
  for (int s=0;s<6;++s){
    const int m = 32>>s;
#pragma unroll
    for (int r=0;r<4;++r){
      float2 p = shflx(v[r], m);
      float sx = (lane & m) ? -1.f : 1.f;
      float2 t = make_float2(fmaf(sx, v[r].x, p.x), fmaf(sx, v[r].y, p.y));
      float2 tm = cmul(t, tws[s][r]);
      v[r] = (lane & m) ? tm : t;
    }
  }
  { float2 a0=v[0], a2=v[2]; v[0]=cadd(a0,a2); v[2]=csub(a0,a2);
    float2 a1=v[1], a3=v[3]; v[1]=cadd(a1,a3); v[3]=cmulj(csub(a1,a3), si); }
  { float2 a=v[0]; v[0]=cadd(a,v[1]); v[1]=csub(a,v[1]);
    float2 c=v[2]; v[2]=cadd(c,v[3]); v[3]=csub(c,v[3]); }
}

// Inverse DIT: input X[brev8(d)] at slot d; natural output at d=4l+r.
__device__ __forceinline__ void fft256_dit4(float2 v[4], int lane,
                                            const float2 tws[6][4], float si){
  { float2 a=v[0]; v[0]=cadd(a,v[1]); v[1]=csub(a,v[1]);
    float2 c=v[2]; v[2]=cadd(c,v[3]); v[3]=csub(c,v[3]); }
  { v[3] = cmulj(v[3], si);
    float2 a0=v[0]; v[0]=cadd(a0,v[2]); v[2]=csub(a0,v[2]);
    float2 a1=v[1]; v[1]=cadd(a1,v[3]); v[3]=csub(a1,v[3]); }
#pragma unroll
  for (int s=5;s>=0;--s){
    const int m = 32>>s;
#pragma unroll
    for (int r=0;r<4;++r){
      float2 wm_ = cmul(v[r], tws[s][r]);
      float2 w = (lane & m) ? wm_ : v[r];
      float2 p = shflx(w, m);
      float sx = (lane & m) ? -1.f : 1.f;
      v[r] = make_float2(fmaf(sx, w.x, p.x), fmaf(sx, w.y, p.y));
    }
  }
}

__device__ __forceinline__ int stage_row(int kw){ return 33*(kw&3) + (kw>>2); }
// Dlds swizzle: spreads rows for 4l+r writes AND 16-row GEMM reads
__device__ __forceinline__ int dslot(int n){ return (((n>>2)&7) ^ ((n&3)<<1)) << 4; }

// ---------------- Pass 1: row rfft, 2 real rows per complex FFT ----------------
__global__ __launch_bounds__(256) void k_rowfft(const float* __restrict__ x, u32* __restrict__ F) {
  __shared__ u32 stage[131*65];
  const int bc = blockIdx.x >> 2, hc = blockIdx.x & 3;
  const int tid = threadIdx.x, wave = tid >> 6, lane = tid & 63;
  Tw T = make_tw(lane, -1.f);
  const int L = brev6(lane);
  const int laneP0 = brev6((64 - L) & 63);
  const int lanePX = 63 - lane;

  for (int rr = 0; rr < 8; ++rr) {
    const int hl0 = wave*16 + rr*2, hl1 = hl0 + 1;
    const float* xa = x + ((size_t)bc*256 + hc*64 + hl0) * 256;
    float2 v[4];
#pragma unroll
    for (int r=0;r<4;++r){ int d = lane + 64*r; v[r] = make_float2(xa[d], xa[256+d]); }
    fft256_dif(v, lane, T);
#define UNSCR(R, RP, C, LP) { \
      float2 z = v[R]; float2 p = shfll(v[RP], LP); \
      float2 A  = make_float2(0.5f*(z.x+p.x), 0.5f*(z.y-p.y)); \
      float2 Bv = make_float2(0.5f*(z.y+p.y), 0.5f*(p.x-z.x)); \
      int kw = 4*L + (C); \
      if (kw <= 128) { int row = stage_row(kw); \
        stage[row*65 + hl0] = pack_bf16(A.x, A.y); \
        stage[row*65 + hl1] = pack_bf16(Bv.x, Bv.y); } }
    UNSCR(0, 0, 0, laneP0)
    UNSCR(1, 1, 2, lanePX)
    UNSCR(2, 3, 1, lanePX)
    UNSCR(3, 2, 3, lanePX)
#undef UNSCR
  }
  __syncthreads();
  for (int idx = tid; idx < 129*64; idx += 256) {
    int kw = idx >> 6, hl = idx & 63;
    F[((size_t)bc*129 + kw)*256 + hc*64 + hl] = stage[stage_row(kw)*65 + hl];
  }
}

// ---------------- Weight prep ----------------
__global__ __launch_bounds__(256) void k_prep_w(const float2* __restrict__ w1,
                                                const float2* __restrict__ w2,
                                                u32* __restrict__ Wt) {
  const int blk = blockIdx.x;      // k*2 + layer
  const int k = blk >> 1, layer = blk & 1;
  const float2* w = (layer == 0 ? w1 : w2) + (size_t)k * 96 * 96;
  u32* out = Wt + (size_t)blk * 18432;
  for (int idx = threadIdx.x; idx < 9216; idx += 256) {
    int o = idx % 96, i = idx / 96;
    float2 v = w[i * 96 + o];
    out[(2 * o) * 96 + i]     = pack_bf16(v.x, -v.y);
    out[(2 * o + 1) * 96 + i] = pack_bf16(v.y, v.x);
  }
}

// ---------------- Fused pass: colFFT + MFMA mix + inv colFFT, per (b,k,kw) -------
// 1024 thr / 16 waves (4 wm x 4 wn). LDS (99072 B) reused in-place:
//   phases A/B: Dlds[n=0..255][kk=0..191] bf16, byte = n*384 + kk*2, XOR dslot(n)
//   phase C:    Clds[c=0..95][n] u32, dword = c*258 + n
// NOTE: bare launch_bounds(1024) -> 4 waves/SIMD resident -> 128-VGPR cap.
// Round-5's (1024,4) clamped VGPR to 64 and spilled to scratch (WRITE_SIZE 2.8x).
#define CM_LDS_BYTES 99072

__global__ __launch_bounds__(1024) void k_colmix(u32* __restrict__ F,
    const u32* __restrict__ Wt,
    const float2* __restrict__ b1, const float2* __restrict__ b2) {
  extern __shared__ char smem[];

  const int bi = (blockIdx.x & 7) * 258 + (blockIdx.x >> 3);  // XCD swizzle (2064 = 8*258)
  const int kw = bi % 129;
  const int bk = bi / 129;
  const int k = bk & 7, b = bk >> 3;
  const int t = threadIdx.x;
  const int lane = t & 63, wave = t >> 6;
  const int wm = wave >> 2, wn = wave & 3;   // M = 4x48, N = 4x64
  const int lrow = lane & 15;
  const int g = lane >> 4;

  const size_t chstride = 129 * 256;
  const size_t colbase = (((size_t)(b*768 + k*96)) * 129 + kw) * 256;

  // ---- phase A: 6 columns/wave, uint4 loads, fwd FFT, scatter to Dlds ----
  {
    uint4 raw[6];
#pragma unroll
    for (int cc = 0; cc < 6; ++cc)
      raw[cc] = *reinterpret_cast<const uint4*>(F + colbase + (size_t)(wave*6 + cc)*chstride + 4*lane);

    float2 tws[6][4];
    make_tws4(lane, -1.f, tws);
    const float s = 1.f/256.f;
#pragma unroll
    for (int pp = 0; pp < 3; ++pp) {
      float2 va[4], vb[4];
      va[0]=unpack_bf16(raw[2*pp].x);   va[1]=unpack_bf16(raw[2*pp].y);
      va[2]=unpack_bf16(raw[2*pp].z);   va[3]=unpack_bf16(raw[2*pp].w);
      vb[0]=unpack_bf16(raw[2*pp+1].x); vb[1]=unpack_bf16(raw[2*pp+1].y);
      vb[2]=unpack_bf16(raw[2*pp+1].z); vb[3]=unpack_bf16(raw[2*pp+1].w);
      fft256_dif4(va, lane, tws, -1.f);
      fft256_dif4(vb, lane, tws, -1.f);
      const int c0 = wave*6 + 2*pp;
#pragma unroll
      for (int r = 0; r < 4; ++r) {
        int n = 4*lane + r;
        int byte = (n*384 + c0*4) ^ dslot(n);
        *reinterpret_cast<uint2*>(smem + byte) =
            make_uint2(pack_bf16(va[r].x*s, va[r].y*s), pack_bf16(vb[r].x*s, vb[r].y*s));
      }
    }
  }
  __syncthreads();

  const bf16x8* W1v = reinterpret_cast<const bf16x8*>(Wt + (size_t)(k*2 + 0) * 18432);
  const bf16x8* W2v = reinterpret_cast<const bf16x8*>(Wt + (size_t)(k*2 + 1) * 18432);

  f32x4 acc[3][4];

  // ---- layer 1: acc = W1 x D ----
#pragma unroll
  for (int mi = 0; mi < 3; ++mi)
#pragma unroll
    for (int ni = 0; ni < 4; ++ni) acc[mi][ni] = (f32x4)0.f;
  {
#pragma unroll
    for (int ks = 0; ks < 6; ++ks) {
      bf16x8 bf[4];
#pragma unroll
      for (int ni = 0; ni < 4; ++ni) {
        int n = wn*64 + ni*16 + lrow;
        int byte = (n*384 + ks*64 + g*16) ^ dslot(n);
        bf[ni] = *reinterpret_cast<bf16x8*>(smem + byte);
      }
      bf16x8 af[3];
#pragma unroll
      for (int mi = 0; mi < 3; ++mi)
        af[mi] = W1v[(wm*48 + mi*16 + lrow)*24 + ks*4 + g];
#pragma unroll
      for (int ni = 0; ni < 4; ++ni)
#pragma unroll
        for (int mi = 0; mi < 3; ++mi)
          acc[mi][ni] = __builtin_amdgcn_mfma_f32_16x16x32_bf16(af[mi], bf[ni], acc[mi][ni], 0, 0, 0);
    }
  }
  __syncthreads();

  // ---- O1 = relu(acc + b1) -> Dlds in place ----
  {
    const float2* b1k = b1 + k * 96;
#pragma unroll
    for (int mi = 0; mi < 3; ++mi) {
      int m0 = wm*48 + mi*16 + 4*g;
      int o0 = m0 >> 1;
      float2 ba = b1k[o0], bb = b1k[o0 + 1];
#pragma unroll
      for (int ni = 0; ni < 4; ++ni) {
        int n = wn*64 + ni*16 + lrow;
        f32x4 v = acc[mi][ni];
        u32 lo = pack_bf16(fmaxf(v[0] + ba.x, 0.f), fmaxf(v[1] + ba.y, 0.f));
        u32 hi = pack_bf16(fmaxf(v[2] + bb.x, 0.f), fmaxf(v[3] + bb.y, 0.f));
        int byte = (n*384 + m0*2) ^ dslot(n);
        *reinterpret_cast<uint2*>(smem + byte) = make_uint2(lo, hi);
      }
    }
  }
  __syncthreads();

  // ---- layer 2: acc = W2 x O1 ----
#pragma unroll
  for (int mi = 0; mi < 3; ++mi)
#pragma unroll
    for (int ni = 0; ni < 4; ++ni) acc[mi][ni] = (f32x4)0.f;
  {
#pragma unroll
    for (int ks = 0; ks < 6; ++ks) {
      bf16x8 bf[4];
#pragma unroll
      for (int ni = 0; ni < 4; ++ni) {
        int n = wn*64 + ni*16 + lrow;
        int byte = (n*384 + ks*64 + g*16) ^ dslot(n);
        bf[ni] = *reinterpret_cast<bf16x8*>(smem + byte);
      }
      bf16x8 af[3];
#pragma unroll
      for (int mi = 0; mi < 3; ++mi)
        af[mi] = W2v[(wm*48 + mi*16 + lrow)*24 + ks*4 + g];
#pragma unroll
      for (int ni = 0; ni < 4; ++ni)
#pragma unroll
        for (int mi = 0; mi < 3; ++mi)
          acc[mi][ni] = __builtin_amdgcn_mfma_f32_16x16x32_bf16(af[mi], bf[ni], acc[mi][ni], 0, 0, 0);
    }
  }
  __syncthreads();

  // ---- epilogue: bias2 + softshrink -> Clds [c][n] (dword = c*258 + n) ----
  {
    u32* Clds = reinterpret_cast<u32*>(smem);
    const float2* b2k = b2 + k * 96;
#pragma unroll
    for (int mi = 0; mi < 3; ++mi) {
      int m0 = wm*48 + mi*16 + 4*g;
      int o0 = m0 >> 1;
      float2 ca = b2k[o0], cb = b2k[o0 + 1];
#pragma unroll
      for (int ni = 0; ni < 4; ++ni) {
        int n = wn*64 + ni*16 + lrow;
        f32x4 v = acc[mi][ni];
        Clds[o0*258 + n]       = pack_bf16(sshrink(v[0] + ca.x), sshrink(v[1] + ca.y));
        Clds[(o0 + 1)*258 + n] = pack_bf16(sshrink(v[2] + cb.x), sshrink(v[3] + cb.y));
      }
    }
  }
  __syncthreads();

  // ---- phase C: inverse FFT per column, uint4 stores back to F ----
  {
    const u32* Clds = reinterpret_cast<const u32*>(smem);
    float2 tws[6][4];
    make_tws4(lane, 1.f, tws);
    const float s = 1.f/256.f;
#pragma unroll
    for (int pp = 0; pp < 3; ++pp) {
      const int c0 = wave*6 + 2*pp;
      float2 va[4], vb[4];
      {
        uint2 q0 = *reinterpret_cast<const uint2*>(Clds + c0*258 + 4*lane);
        uint2 q1 = *reinterpret_cast<const uint2*>(Clds + c0*258 + 4*lane + 2);
        va[0]=unpack_bf16(q0.x); va[1]=unpack_bf16(q0.y);
        va[2]=unpack_bf16(q1.x); va[3]=unpack_bf16(q1.y);
        uint2 q2 = *reinterpret_cast<const uint2*>(Clds + (c0+1)*258 + 4*lane);
        uint2 q3 = *reinterpret_cast<const uint2*>(Clds + (c0+1)*258 + 4*lane + 2);
        vb[0]=unpack_bf16(q2.x); vb[1]=unpack_bf16(q2.y);
        vb[2]=unpack_bf16(q3.x); vb[3]=unpack_bf16(q3.y);
      }
      fft256_dit4(va, lane, tws, 1.f);
      fft256_dit4(vb, lane, tws, 1.f);
      uint4 oa, ob;
      oa.x = pack_bf16(va[0].x*s, va[0].y*s); oa.y = pack_bf16(va[1].x*s, va[1].y*s);
      oa.z = pack_bf16(va[2].x*s, va[2].y*s); oa.w = pack_bf16(va[3].x*s, va[3].y*s);
      ob.x = pack_bf16(vb[0].x*s, vb[0].y*s); ob.y = pack_bf16(vb[1].x*s, vb[1].y*s);
      ob.z = pack_bf16(vb[2].x*s, vb[2].y*s); ob.w = pack_bf16(vb[3].x*s, vb[3].y*s);
      *reinterpret_cast<uint4*>(F + colbase + (size_t)c0*chstride + 4*lane) = oa;
      *reinterpret_cast<uint4*>(F + colbase + (size_t)(c0+1)*chstride + 4*lane) = ob;
    }
  }
}

// ---------------- Pass 5: row irfft (Hermitian ext), 2 rows per FFT, + bias ------
__global__ __launch_bounds__(256) void k_rowifft(const u32* __restrict__ F,
                                                 const float* __restrict__ x,
                                                 float* __restrict__ out) {
  __shared__ u32 stage[131*65];
  const int bc = blockIdx.x >> 2, hc = blockIdx.x & 3;
  const int tid = threadIdx.x, wave = tid >> 6, lane = tid & 63;
  Tw T = make_tw(lane, 1.f);
  for (int idx = tid; idx < 129*64; idx += 256) {
    int kw = idx >> 6, hl = idx & 63;
    stage[stage_row(kw)*65 + hl] = F[((size_t)bc*129 + kw)*256 + hc*64 + hl];
  }
  __syncthreads();

  const int L = brev6(lane);
  for (int rr = 0; rr < 8; ++rr) {
    const int hl0 = wave*16 + rr*2, hl1 = hl0 + 1;
    float2 v[4];
#pragma unroll
    for (int r=0;r<4;++r) {
      int c = ((r&1)<<1) | (r>>1);
      int kw = 4*L + c;
      int src = (kw <= 128) ? kw : 256 - kw;
      float sg = (kw <= 128) ? 1.f : -1.f;
      int row = stage_row(src);
      float2 a = unpack_bf16(stage[row*65 + hl0]);
      float2 b = unpack_bf16(stage[row*65 + hl1]);
      a.y *= sg; b.y *= sg;
      if (kw == 0 || kw == 128) { a.y = 0.f; b.y = 0.f; }
      v[r] = make_float2(a.x - b.y, a.y + b.x);
    }
    fft256_dit(v, lane, T);
    const float* xa = x   + ((size_t)bc*256 + hc*64 + hl0) * 256;
    float*       oa = out + ((size_t)bc*256 + hc*64 + hl0) * 256;
#pragma unroll
    for (int r=0;r<4;++r) {
      int d = lane + 64*r;
      oa[d]       = v[r].x + xa[d];
      oa[256 + d] = v[r].y + xa[256 + d];
    }
  }
}

extern "C" void kernel_launch(void* const* d_in, const int* in_sizes, int n_in,
                              void* d_out, int out_size, void* d_ws, size_t ws_size,
                              hipStream_t stream) {
  const float* x   = (const float*)d_in[0];
  const float2* w1 = (const float2*)d_in[1];
  const float2* b1 = (const float2*)d_in[2];
  const float2* w2 = (const float2*)d_in[3];
  const float2* b2 = (const float2*)d_in[4];
  float* out = (float*)d_out;
  u32* F = (u32*)d_ws;            // 1536*129*256*4 B ~ 203 MB
  u32* Wt = (u32*)d_out;          // d_out head as scratch; overwritten by k_rowifft

  (void)hipFuncSetAttribute(reinterpret_cast<const void*>(k_colmix),
                            hipFuncAttributeMaxDynamicSharedMemorySize, CM_LDS_BYTES);

  const int n_rows_blocks = 1536 * 4;
  const int n_cm_blocks   = 2 * 8 * 129;   // 2064 = 8 * 258

  k_prep_w<<<16, 256, 0, stream>>>(w1, w2, Wt);
  k_rowfft<<<n_rows_blocks, 256, 0, stream>>>(x, F);
  k_colmix<<<n_cm_blocks, 1024, CM_LDS_BYTES, stream>>>(F, Wt, b1, b2);
  k_rowifft<<<n_rows_blocks, 256, 0, stream>>>(F, x, out);
}